// Round 5
// baseline (509.725 us; speedup 1.0000x reference)
//
#include <hip/hip_runtime.h>
#include <cmath>
#include <cfloat>

#define NUM_EMB 1024
#define EMB_DIM 256
#define BATCH 32
#define SEQ 2048
#define NROWS 65536            // BATCH*SEQ
// d_out offsets (floats): [loss | quantized (b,c,l) | perplexity | encodings (N,K)]
#define Q_OFF 1
#define PERP_OFF 16777217
#define ENC_OFF 16777218
// ws offsets (bytes)
#define WS_IDX 0
#define WS_E2     (NROWS * 4)
#define WS_COUNTS (WS_E2 + NUM_EMB * 4)
#define WS_SSE    (WS_COUNTS + NUM_EMB * 4)
#define WS_EMX    (WS_SSE + 1024 * 8)

typedef __attribute__((ext_vector_type(8))) short short8v;
typedef __attribute__((ext_vector_type(16))) float f32x16;
#define MFMA(a,b,c) __builtin_amdgcn_mfma_f32_32x32x16_bf16(a,b,c,0,0,0)

// square with a barrier so the compiler cannot contract x*x into a following add
__device__ __forceinline__ float sqg(float x) {
    float s = x * x;
    asm volatile("" : "+v"(s));
    return s;
}

// RNE float->bf16
__device__ __forceinline__ unsigned short f2bf(float f) {
    unsigned u = __float_as_uint(f);
    unsigned r = u + 0x7FFFu + ((u >> 16) & 1u);
    return (unsigned short)(r >> 16);
}

// order-preserving float<->uint maps
__device__ __forceinline__ unsigned f2ord(float f) {
    unsigned u = __float_as_uint(f);
    return (u & 0x80000000u) ? ~u : (u | 0x80000000u);
}
__device__ __forceinline__ float ord2f(unsigned o) {
    unsigned u = (o & 0x80000000u) ? (o & 0x7FFFFFFFu) : ~o;
    return __uint_as_float(u);
}

// exact OpenBLAS-order dot: single accumulator, ascending d, fmaf
__device__ float exact_dot256(const float* __restrict__ xb, const float* __restrict__ er) {
    float acc = 0.0f;
    for (int d = 0; d < 256; d += 8) {
        float4 ea = *(const float4*)(er + d);
        float4 eb = *(const float4*)(er + d + 4);
        float x0 = xb[(size_t)(d + 0) * 2048];
        float x1 = xb[(size_t)(d + 1) * 2048];
        float x2 = xb[(size_t)(d + 2) * 2048];
        float x3 = xb[(size_t)(d + 3) * 2048];
        float x4 = xb[(size_t)(d + 4) * 2048];
        float x5 = xb[(size_t)(d + 5) * 2048];
        float x6 = xb[(size_t)(d + 6) * 2048];
        float x7 = xb[(size_t)(d + 7) * 2048];
        acc = __builtin_fmaf(x0, ea.x, acc);
        acc = __builtin_fmaf(x1, ea.y, acc);
        acc = __builtin_fmaf(x2, ea.z, acc);
        acc = __builtin_fmaf(x3, ea.w, acc);
        acc = __builtin_fmaf(x4, eb.x, acc);
        acc = __builtin_fmaf(x5, eb.y, acc);
        acc = __builtin_fmaf(x6, eb.z, acc);
        acc = __builtin_fmaf(x7, eb.w, acc);
    }
    return acc;
}

// numpy pairwise sum of squares over 256 elements (AVX512 path replica)
template <int STRIDE>
__device__ float np_sumsq256(const float* __restrict__ p) {
    float total = 0.0f;
#pragma unroll
    for (int h = 0; h < 2; ++h) {
        const int base = 128 * h;
        float c[16];
#pragma unroll
        for (int l = 0; l < 16; ++l) {
            float t0 = sqg(p[(size_t)(base + l) * STRIDE]);
            float t1 = sqg(p[(size_t)(base + 16 + l) * STRIDE]);
            float t2 = sqg(p[(size_t)(base + 32 + l) * STRIDE]);
            float t3 = sqg(p[(size_t)(base + 48 + l) * STRIDE]);
            float t4 = sqg(p[(size_t)(base + 64 + l) * STRIDE]);
            float t5 = sqg(p[(size_t)(base + 80 + l) * STRIDE]);
            float t6 = sqg(p[(size_t)(base + 96 + l) * STRIDE]);
            float t7 = sqg(p[(size_t)(base + 112 + l) * STRIDE]);
            c[l] = ((t0 + t1) + (t2 + t3)) + ((t4 + t5) + (t6 + t7));
        }
        float u[8];
#pragma unroll
        for (int l = 0; l < 8; ++l) u[l] = c[l] + c[l + 8];
        float v[4];
#pragma unroll
        for (int l = 0; l < 4; ++l) v[l] = u[l] + u[l + 4];
        float w0 = v[0] + v[2];
        float w1 = v[1] + v[3];
        float hh = w0 + w1;
        total = (h == 0) ? hh : (total + hh);
    }
    return total;
}

__global__ void k_zero(int* __restrict__ counts, unsigned* __restrict__ emx) {
    int i = blockIdx.x * blockDim.x + threadIdx.x;
    if (i < NUM_EMB) counts[i] = 0;
    if (i == NUM_EMB) *emx = 0u;
}

__global__ __launch_bounds__(256) void k_e2(const float* __restrict__ emb,
                                            float* __restrict__ e2,
                                            unsigned* __restrict__ emx) {
    int k = blockIdx.x * 256 + threadIdx.x;
    float v = np_sumsq256<1>(emb + (size_t)k * EMB_DIM);
    e2[k] = v;
    __shared__ float red[256];
    red[threadIdx.x] = sqrtf(v);
    __syncthreads();
    for (int s = 128; s > 0; s >>= 1) {
        if (threadIdx.x < s) red[threadIdx.x] = fmaxf(red[threadIdx.x], red[threadIdx.x + s]);
        __syncthreads();
    }
    if (threadIdx.x == 0) atomicMax(emx, __float_as_uint(red[0]));
}

// bf16 E image for DIRECT coalesced B-fragment loads:
// ebf[p][c] = 16 bytes = e[c][8p .. 8p+7] bf16   (p = 0..31, c = 0..1023)
__global__ __launch_bounds__(256) void k_prep_e(const float* __restrict__ emb,
                                                char* __restrict__ ebf) {
    int t = blockIdx.x * 256 + threadIdx.x;   // 8192 threads
    int c = t & 1023;
    int s = t >> 10;                          // 0..7
#pragma unroll
    for (int g = 0; g < 4; ++g) {
        int p = s + 8 * g;
        const float* e = emb + (size_t)c * EMB_DIM + 8 * p;
        unsigned h[8];
#pragma unroll
        for (int j = 0; j < 8; ++j) h[j] = f2bf(e[j]);
        uint4 w;
        w.x = h[0] | (h[1] << 16);
        w.y = h[2] | (h[3] << 16);
        w.z = h[4] | (h[5] << 16);
        w.w = h[6] | (h[7] << 16);
        *(uint4*)(ebf + ((size_t)p << 14) + ((size_t)c << 4)) = w;
    }
}

// one 64x64-per-wave MFMA pass over 256 codes (identical in both phases)
__device__ __forceinline__ void mfma_pass(
    const char* __restrict__ ebf, const char* __restrict__ pool,
    int c0, int c1, int rb0, int rb1, int rsw, int lh,
    f32x16& acc00, f32x16& acc01, f32x16& acc10, f32x16& acc11)
{
#pragma unroll
    for (int i = 0; i < 16; ++i) { acc00[i] = 0.f; acc01[i] = 0.f; acc10[i] = 0.f; acc11[i] = 0.f; }
    const char* bp0 = ebf + ((size_t)lh << 14);
    short8v bc0 = *(const short8v*)(bp0 + ((size_t)c0 << 4));
    short8v bc1 = *(const short8v*)(bp0 + ((size_t)c1 << 4));
    for (int ks = 0; ks < 16; ++ks) {
        short8v bn0, bn1;
        if (ks < 15) {
            const char* nb = ebf + ((size_t)(2 * ks + 2 + lh) << 14);
            bn0 = *(const short8v*)(nb + ((size_t)c0 << 4));
            bn1 = *(const short8v*)(nb + ((size_t)c1 << 4));
        }
        const int koff = 32 * ks + 16 * lh;
        short8v a0 = *(const short8v*)(pool + rb0 + (koff ^ rsw));
        short8v a1 = *(const short8v*)(pool + rb1 + (koff ^ rsw));
        acc00 = MFMA(a0, bc0, acc00);
        acc01 = MFMA(a0, bc1, acc01);
        acc10 = MFMA(a1, bc0, acc10);
        acc11 = MFMA(a1, bc1, acc11);
        if (ks < 15) { bc0 = bn0; bc1 = bn1; }
    }
}

// Fused distance+argmin, two-phase:
//   phase 1: MFMA passes keeping per-lane in-register running min (no cross-lane, no barriers)
//   one cross-lane reduce -> per-row global min -> threshold
//   phase 2: identical MFMA rerun, collect candidates vs FINAL threshold (exact set)
//   queue rescore with bit-exact numpy/OpenBLAS arithmetic.
__global__ __launch_bounds__(256, 3) void k_dist(
    const float* __restrict__ in, const char* __restrict__ ebf,
    const float* __restrict__ emb, const float* __restrict__ e2g,
    const unsigned* __restrict__ emxp,
    int* __restrict__ idx, int* __restrict__ counts)
{
    __shared__ __align__(16) char pool[32768];  // X tile [64 rows][512B], swizzled
    __shared__ float vpart[64][8];
    __shared__ float A_lds[64];
    __shared__ float thrRow[64];
    __shared__ unsigned rowMinU[64];
    __shared__ int rowCnt[64];
    __shared__ int rowList[64 * 16];
    __shared__ unsigned long long rowBest[64];

    const int tid = threadIdx.x;
    const int n0 = blockIdx.x << 6;
    const int b = n0 >> 11;
    const int l0 = n0 & 2047;
    const int lane = tid & 63;
    const int wv = tid >> 6;
    const int lm = lane & 31;
    const int lh = lane >> 5;

    if (tid < 64) { rowMinU[tid] = 0xFFFFFFFFu; rowCnt[tid] = 0; rowBest[tid] = ~0ull; }

    // ---- stage X (bf16, 16-slot XOR swizzle) + exact numpy-pairwise rowsum ----
    {
        const int o = wv;               // d residue (mod 4)
        const int r = lane;             // row 0..63
        const float* xcol = in + (size_t)b * 524288 + l0 + r;
#pragma unroll
        for (int h = 0; h < 2; ++h) {
            float tarr[32];
#pragma unroll
            for (int it = 0; it < 32; ++it) {
                const int d = 128 * h + 4 * it + o;
                float v = xcol[(size_t)d * 2048];
                *(unsigned short*)(pool + r * 512 + ((2 * d) ^ ((r & 15) << 4))) = f2bf(v);
                tarr[it] = sqg(v);
            }
            float cj[4];
#pragma unroll
            for (int j = 0; j < 4; ++j)
                cj[j] = ((tarr[j] + tarr[4 + j]) + (tarr[8 + j] + tarr[12 + j]))
                      + ((tarr[16 + j] + tarr[20 + j]) + (tarr[24 + j] + tarr[28 + j]));
            vpart[r][h * 4 + o] = (cj[0] + cj[2]) + (cj[1] + cj[3]);
        }
    }
    __syncthreads();
    if (tid < 64) {
        const float* vp = vpart[tid];
        float h0 = (vp[0] + vp[2]) + (vp[1] + vp[3]);
        float h1 = (vp[4] + vp[6]) + (vp[5] + vp[7]);
        A_lds[tid] = h0 + h1;
    }
    __syncthreads();

    const int rsw = (lm & 15) << 4;
    const int rb0 = lm * 512;
    const int rb1 = (32 + lm) * 512;

    // ---- phase 1: per-lane running min only ----
    f32x16 pm0, pm1;
#pragma unroll
    for (int i = 0; i < 16; ++i) { pm0[i] = FLT_MAX; pm1[i] = FLT_MAX; }

    for (int pass = 0; pass < 4; ++pass) {
        const int c0 = pass * 256 + wv * 64 + lm;
        const int c1 = c0 + 32;
        f32x16 acc00, acc01, acc10, acc11;
        mfma_pass(ebf, pool, c0, c1, rb0, rb1, rsw, lh, acc00, acc01, acc10, acc11);
        const float e20 = e2g[c0];
        const float e21 = e2g[c1];
#pragma unroll
        for (int i = 0; i < 16; ++i) {
            float s00 = __builtin_fmaf(-2.0f, acc00[i], e20);
            float s01 = __builtin_fmaf(-2.0f, acc01[i], e21);
            float s10 = __builtin_fmaf(-2.0f, acc10[i], e20);
            float s11 = __builtin_fmaf(-2.0f, acc11[i], e21);
            pm0[i] = fminf(pm0[i], fminf(s00, s01));
            pm1[i] = fminf(pm1[i], fminf(s10, s11));
        }
    }
    // one cross-lane reduce (32 independent 5-step chains)
#pragma unroll
    for (int mk = 1; mk < 32; mk <<= 1) {
#pragma unroll
        for (int i = 0; i < 16; ++i) {
            pm0[i] = fminf(pm0[i], __shfl_xor(pm0[i], mk));
            pm1[i] = fminf(pm1[i], __shfl_xor(pm1[i], mk));
        }
    }
    if (lm == 0) {
#pragma unroll
        for (int i = 0; i < 16; ++i) {
            const int base = (i & 3) + 8 * (i >> 2) + 4 * lh;
            atomicMin(&rowMinU[base], f2ord(pm0[i]));
            atomicMin(&rowMinU[base + 32], f2ord(pm1[i]));
        }
    }
    __syncthreads();
    const float EMX = __uint_as_float(*emxp);
    if (tid < 64) {
        thrRow[tid] = ord2f(rowMinU[tid]) + (0.015625f * sqrtf(A_lds[tid]) * EMX + 2.0e-4f);
    }
    __syncthreads();

    // ---- phase 2: identical MFMA rerun, collect vs final threshold ----
    for (int pass = 0; pass < 4; ++pass) {
        const int c0 = pass * 256 + wv * 64 + lm;
        const int c1 = c0 + 32;
        f32x16 acc00, acc01, acc10, acc11;
        mfma_pass(ebf, pool, c0, c1, rb0, rb1, rsw, lh, acc00, acc01, acc10, acc11);
        const float e20 = e2g[c0];
        const float e21 = e2g[c1];
#pragma unroll
        for (int i = 0; i < 16; ++i) {
            const int base = (i & 3) + 8 * (i >> 2) + 4 * lh;
            float s00 = __builtin_fmaf(-2.0f, acc00[i], e20);
            float s01 = __builtin_fmaf(-2.0f, acc01[i], e21);
            float s10 = __builtin_fmaf(-2.0f, acc10[i], e20);
            float s11 = __builtin_fmaf(-2.0f, acc11[i], e21);
            if (s00 <= thrRow[base])      { int p = atomicAdd(&rowCnt[base], 1);      if (p < 16) rowList[base * 16 + p]        = c0; }
            if (s01 <= thrRow[base])      { int p = atomicAdd(&rowCnt[base], 1);      if (p < 16) rowList[base * 16 + p]        = c1; }
            if (s10 <= thrRow[base + 32]) { int p = atomicAdd(&rowCnt[base + 32], 1); if (p < 16) rowList[(base + 32) * 16 + p] = c0; }
            if (s11 <= thrRow[base + 32]) { int p = atomicAdd(&rowCnt[base + 32], 1); if (p < 16) rowList[(base + 32) * 16 + p] = c1; }
        }
    }
    __syncthreads();

    // ---- rescore every listed candidate (exact bits), packed argmin w/ min-k ties ----
    for (int e = tid; e < 1024; e += 256) {
        const int rr = e >> 4;
        const int s = e & 15;
        const int cnt = rowCnt[rr];
        if (s >= (cnt < 16 ? cnt : 16)) continue;
        const int k = rowList[e];
        const float* xb = in + (size_t)b * 524288 + (l0 + rr);
        float acc2 = exact_dot256(xb, emb + (size_t)k * EMB_DIM);
        float t = A_lds[rr] + e2g[k];
        float dist = t - 2.0f * acc2;
        unsigned long long pk = ((unsigned long long)f2ord(dist) << 32) | (unsigned)k;
        atomicMin(&rowBest[rr], pk);
    }
    __syncthreads();

    if (tid < 64) {
        const int cnt = rowCnt[tid];
        int bk;
        if (cnt > 16) {
            // overflow (prob ~0): exact full scan
            const float* xb = in + (size_t)b * 524288 + (l0 + tid);
            const float A = A_lds[tid];
            float bestd = FLT_MAX;
            bk = 0x7FFFFFFF;
            for (int k = 0; k < NUM_EMB; ++k) {
                float acc2 = exact_dot256(xb, emb + (size_t)k * EMB_DIM);
                float t = A + e2g[k];
                float dist = t - 2.0f * acc2;
                if (dist < bestd || (dist == bestd && k < bk)) { bestd = dist; bk = k; }
            }
        } else {
            bk = (int)(rowBest[tid] & 0xFFFFFFFFull);
        }
        idx[n0 + tid] = bk;
        atomicAdd(&counts[bk], 1);
    }
}

// quantized output: out[b,c,l] = emb[idx[n], c] via LDS transpose; fused SSE partials
__global__ __launch_bounds__(256) void k_quant(
    const float* __restrict__ in, const float* __restrict__ emb,
    const int* __restrict__ idx, float* __restrict__ qout, double* __restrict__ ssep)
{
    __shared__ float T[256][65];
    __shared__ int lidx[64];
    __shared__ double rd[256];
    const int tid = threadIdx.x;
    const int bid = blockIdx.x;
    const int b = bid >> 5;
    const int l0 = (bid & 31) << 6;
    const int nb = b * SEQ + l0;
    if (tid < 64) lidx[tid] = idx[nb + tid];
    __syncthreads();
#pragma unroll 4
    for (int l = 0; l < 64; ++l) {
        T[tid][l] = emb[(size_t)lidx[l] * EMB_DIM + tid];
    }
    __syncthreads();
    double sse = 0.0;
    const int lo = tid & 63;
    const int ch = tid >> 6;
    for (int it = 0; it < 64; ++it) {
        const int c = (it << 2) + ch;
        const size_t g = (size_t)b * (EMB_DIM * SEQ) + (size_t)c * SEQ + l0 + lo;
        const float q = T[c][lo];
        const float x = in[g];
        qout[g] = q;
        const float d = q - x;
        sse += (double)d * (double)d;
    }
    rd[tid] = sse;
    __syncthreads();
    for (int s = 128; s > 0; s >>= 1) {
        if (tid < s) rd[tid] += rd[tid + s];
        __syncthreads();
    }
    if (tid == 0) ssep[bid] = rd[0];
}

// one-hot encodings: float4 stores, every element rewritten every call
__global__ __launch_bounds__(256) void k_enc(const int* __restrict__ idx, float* __restrict__ enc) {
    const int gid = blockIdx.x * 256 + threadIdx.x;   // 16777216 threads
    const int n = gid >> 8;
    const int kk = (gid & 255) << 2;
    const int e = idx[n];
    float4 v;
    v.x = (e == kk) ? 1.0f : 0.0f;
    v.y = (e == kk + 1) ? 1.0f : 0.0f;
    v.z = (e == kk + 2) ? 1.0f : 0.0f;
    v.w = (e == kk + 3) ? 1.0f : 0.0f;
    *(float4*)(enc + (size_t)n * NUM_EMB + kk) = v;
}

__global__ __launch_bounds__(256) void k_final(const double* __restrict__ ssep,
                                               const int* __restrict__ counts,
                                               float* __restrict__ out)
{
    __shared__ double rd[256];
    const int tid = threadIdx.x;
    double s = 0.0;
    for (int i = tid; i < 1024; i += 256) s += ssep[i];
    rd[tid] = s;
    __syncthreads();
    for (int st = 128; st > 0; st >>= 1) {
        if (tid < st) rd[tid] += rd[tid + st];
        __syncthreads();
    }
    const double total = rd[0];
    __syncthreads();
    double pl = 0.0;
    for (int k = tid; k < 1024; k += 256) {
        const double p = (double)counts[k] * (1.0 / 65536.0);
        pl += p * log(p + 1e-10);
    }
    rd[tid] = pl;
    __syncthreads();
    for (int st = 128; st > 0; st >>= 1) {
        if (tid < st) rd[tid] += rd[tid + st];
        __syncthreads();
    }
    if (tid == 0) {
        out[0] = (float)(1.25 * (total * (1.0 / 16777216.0)));
        out[PERP_OFF] = (float)exp(-rd[0]);
    }
}

extern "C" void kernel_launch(void* const* d_in, const int* in_sizes, int n_in,
                              void* d_out, int out_size, void* d_ws, size_t ws_size,
                              hipStream_t stream)
{
    const float* in  = (const float*)d_in[0];
    const float* emb = (const float*)d_in[1];
    float* out = (float*)d_out;
    char* ws = (char*)d_ws;
    int*      idx    = (int*)(ws + WS_IDX);
    float*    e2     = (float*)(ws + WS_E2);
    int*      counts = (int*)(ws + WS_COUNTS);
    double*   ssep   = (double*)(ws + WS_SSE);
    unsigned* emx    = (unsigned*)(ws + WS_EMX);

    // bf16 E image carved from the encodings output region (overwritten by k_enc)
    char* ebf = (char*)d_out + ((size_t)ENC_OFF * 4 + 8);   // 16B-aligned, 512 KB

    k_zero<<<dim3(5), dim3(256), 0, stream>>>(counts, emx);
    k_e2<<<dim3(4), dim3(256), 0, stream>>>(emb, e2, emx);
    k_prep_e<<<dim3(32), dim3(256), 0, stream>>>(emb, ebf);
    k_dist<<<dim3(1024), dim3(256), 0, stream>>>(in, ebf, emb, e2, emx, idx, counts);
    k_quant<<<dim3(1024), dim3(256), 0, stream>>>(in, emb, idx, out + Q_OFF, ssep);
    k_enc<<<dim3(65536), dim3(256), 0, stream>>>(idx, out + ENC_OFF);
    k_final<<<dim3(1), dim3(256), 0, stream>>>(ssep, counts, out);
}